// Round 1
// baseline (985.859 us; speedup 1.0000x reference)
//
#include <hip/hip_runtime.h>
#include <math.h>

#define RR 8
#define NN 128
#define DD 512
#define HH 256
#define KTOP 64
#define KB 32
#define MT 64

// ws layout (bytes)
#define WS_LOGITS_OFF 0              // 16384 f32 accumulators
#define WS_TOPK_OFF   65536          // 64 int32
#define WS_PF_OFF     65792          // 64*512 f32 pair feats
#define WS_H_OFF      196864         // 4096*256 f32 pre-relu h accumulators

// -------- Kernel 1: logits[r,i,j] first-MLP, accumulated over r ----------
// grid (NN/MT, NN, RR), block 256.  Per wg: 64 j-rows x 256 h-cols x K=512.
// A[j][k] = obj[r,i,k]*obj[r,j,k] + geo[r,i,j,k] generated on the fly.
__global__ __launch_bounds__(256) void k1_pair_mlp(
    const float* __restrict__ obj, const float* __restrict__ geo,
    const float* __restrict__ W1, const float* __restrict__ b1,
    const float* __restrict__ w2, float* __restrict__ logits_acc)
{
    const int jb = blockIdx.x, i = blockIdx.y, r = blockIdx.z;
    const int j0 = jb * MT;
    const int tid = threadIdx.x;
    const int tx = tid & 15, ty = tid >> 4;

    __shared__ float sObjI[DD];
    __shared__ __align__(16) float sA[KB][MT + 4];   // transposed A, stride 68 (272B, 16B-mult)
    __shared__ __align__(16) float sB[KB][HH];

    const float* objI = obj + (size_t)(r * NN + i) * DD;
    for (int t = tid; t < DD; t += 256) sObjI[t] = objI[t];

    float acc[4][16];
#pragma unroll
    for (int m = 0; m < 4; ++m)
#pragma unroll
        for (int n = 0; n < 16; ++n) acc[m][n] = 0.f;

    const float* geoBase = geo + (size_t)((r * NN + i) * NN + j0) * DD;
    const float* objJ = obj + (size_t)(r * NN + j0) * DD;

    for (int kc = 0; kc < DD / KB; ++kc) {
        const int k0 = kc * KB;
        __syncthreads();
        // stage B chunk: W1[k0..k0+31][0..255]
#pragma unroll
        for (int p = 0; p < 8; ++p) {
            int f = tid + p * 256;
            int kk = f >> 6, c = (f & 63) << 2;
            *(float4*)&sB[kk][c] = *(const float4*)&W1[(size_t)(k0 + kk) * HH + c];
        }
        // stage A chunk (generate obj2obj), store transposed
#pragma unroll
        for (int p = 0; p < 2; ++p) {
            int f = tid + p * 256;
            int j = f >> 3, kk = (f & 7) << 2;
            float4 g = *(const float4*)(geoBase + (size_t)j * DD + k0 + kk);
            float4 o = *(const float4*)(objJ   + (size_t)j * DD + k0 + kk);
            sA[kk + 0][j] = sObjI[k0 + kk + 0] * o.x + g.x;
            sA[kk + 1][j] = sObjI[k0 + kk + 1] * o.y + g.y;
            sA[kk + 2][j] = sObjI[k0 + kk + 2] * o.z + g.z;
            sA[kk + 3][j] = sObjI[k0 + kk + 3] * o.w + g.w;
        }
        __syncthreads();
#pragma unroll 8
        for (int kk = 0; kk < KB; ++kk) {
            float4 a4 = *(const float4*)&sA[kk][ty << 2];
            float av[4] = {a4.x, a4.y, a4.z, a4.w};
#pragma unroll
            for (int n4 = 0; n4 < 4; ++n4) {
                float4 b4 = *(const float4*)&sB[kk][(n4 << 6) + (tx << 2)];
                float bv[4] = {b4.x, b4.y, b4.z, b4.w};
#pragma unroll
                for (int m = 0; m < 4; ++m)
#pragma unroll
                    for (int c = 0; c < 4; ++c)
                        acc[m][(n4 << 2) + c] = fmaf(av[m], bv[c], acc[m][(n4 << 2) + c]);
            }
        }
    }
    // epilogue: relu(acc + b1)·w2, reduce over h, accumulate over r
    float pr[4] = {0.f, 0.f, 0.f, 0.f};
#pragma unroll
    for (int n4 = 0; n4 < 4; ++n4)
#pragma unroll
        for (int c = 0; c < 4; ++c) {
            int h = (n4 << 6) + (tx << 2) + c;
            float bb = b1[h], w = w2[h];
#pragma unroll
            for (int m = 0; m < 4; ++m)
                pr[m] += fmaxf(acc[m][(n4 << 2) + c] + bb, 0.f) * w;
        }
#pragma unroll
    for (int m = 0; m < 4; ++m) {
        for (int off = 1; off < 16; off <<= 1) pr[m] += __shfl_xor(pr[m], off);
        if (tx == 0)
            atomicAdd(&logits_acc[i * NN + j0 + (ty << 2) + m], pr[m]);
    }
}

// -------- Kernel 2: finalize o2o logits, write output 0, top-64, output 2 ----
__global__ __launch_bounds__(1024) void k2_topk(
    const float* __restrict__ logits_acc, const float* __restrict__ mask,
    const float* __restrict__ b2a, float* __restrict__ out,
    int* __restrict__ ws_topk)
{
    const int t = threadIdx.x;
    const float bias = b2a[0];
    float v[16];
#pragma unroll
    for (int e = 0; e < 16; ++e) {
        int idx = e * 1024 + t;
        float lg = logits_acc[idx] * 0.125f + bias;
        out[idx] = lg;                                   // output 0: o2o_logits
        v[e] = (1.f / (1.f + expf(-lg))) * mask[idx];    // pair_probs
    }
    __shared__ float sVal[16];
    __shared__ int sIdx[16];
    __shared__ int sWin;
    for (int it = 0; it < KTOP; ++it) {
        float bv = -1.f; int bi = 0x7fffffff;
#pragma unroll
        for (int e = 0; e < 16; ++e)
            if (v[e] > bv) { bv = v[e]; bi = e * 1024 + t; }
        // wave reduce (val desc, idx asc)
        for (int off = 1; off < 64; off <<= 1) {
            float ov = __shfl_xor(bv, off);
            int   oi = __shfl_xor(bi, off);
            if (ov > bv || (ov == bv && oi < bi)) { bv = ov; bi = oi; }
        }
        int wave = t >> 6, lane = t & 63;
        if (lane == 0) { sVal[wave] = bv; sIdx[wave] = bi; }
        __syncthreads();
        if (t == 0) {
            float B = -2.f; int I = 0x7fffffff;
            for (int w = 0; w < 16; ++w)
                if (sVal[w] > B || (sVal[w] == B && sIdx[w] < I)) { B = sVal[w]; I = sIdx[w]; }
            sWin = I;
            ws_topk[it] = I;
            out[20480 + it] = (float)I;                  // output 2: topk index
        }
        __syncthreads();
        int wi = sWin;
        if ((wi & 1023) == t) v[wi >> 10] = -1.f;        // consume winner
        __syncthreads();
    }
}

// -------- Kernel 3: gather averaged pair features for top-64 ----------
__global__ __launch_bounds__(256) void k3_gather(
    const float* __restrict__ obj, const float* __restrict__ geo,
    const int* __restrict__ ws_topk, float* __restrict__ pf)
{
    const int tix = blockIdx.x;            // 0..63
    const int idx = ws_topk[tix];
    const int i = idx >> 7, j = idx & 127;
    for (int dd = threadIdx.x; dd < DD; dd += 256) {
        float s = 0.f;
#pragma unroll
        for (int r = 0; r < RR; ++r) {
            float oi = obj[(size_t)(r * NN + i) * DD + dd];
            float oj = obj[(size_t)(r * NN + j) * DD + dd];
            float g  = geo[((size_t)(r * NN + i) * NN + j) * DD + dd];
            s += oi * oj + g;
        }
        pf[tix * DD + dd] = s * 0.125f;
    }
}

// -------- Kernel 4a: p2p first-layer GEMM (split-K into ws_h) ----------
// grid (4, 64): blockIdx.x = K-slice (128 each), blockIdx.y = a.
__global__ __launch_bounds__(256) void k4_p2p_mlp(
    const float* __restrict__ pf, const float* __restrict__ W1,
    float* __restrict__ h_acc)
{
    const int ks = blockIdx.x, a = blockIdx.y;
    const int tid = threadIdx.x;
    const int tx = tid & 15, ty = tid >> 4;

    __shared__ float sPfA[DD];
    __shared__ __align__(16) float sA[KB][MT + 4];
    __shared__ __align__(16) float sB[KB][HH];

    const float* pfA = pf + (size_t)a * DD;
    for (int t = tid; t < DD; t += 256) sPfA[t] = pfA[t];

    float acc[4][16];
#pragma unroll
    for (int m = 0; m < 4; ++m)
#pragma unroll
        for (int n = 0; n < 16; ++n) acc[m][n] = 0.f;

    for (int kc = 0; kc < 4; ++kc) {
        const int k0 = ks * 128 + kc * KB;
        __syncthreads();
#pragma unroll
        for (int p = 0; p < 8; ++p) {
            int f = tid + p * 256;
            int kk = f >> 6, c = (f & 63) << 2;
            *(float4*)&sB[kk][c] = *(const float4*)&W1[(size_t)(k0 + kk) * HH + c];
        }
#pragma unroll
        for (int p = 0; p < 2; ++p) {
            int f = tid + p * 256;
            int j = f >> 3, kk = (f & 7) << 2;
            float4 o = *(const float4*)(pf + (size_t)j * DD + k0 + kk);
            sA[kk + 0][j] = sPfA[k0 + kk + 0] * o.x;
            sA[kk + 1][j] = sPfA[k0 + kk + 1] * o.y;
            sA[kk + 2][j] = sPfA[k0 + kk + 2] * o.z;
            sA[kk + 3][j] = sPfA[k0 + kk + 3] * o.w;
        }
        __syncthreads();
#pragma unroll 8
        for (int kk = 0; kk < KB; ++kk) {
            float4 a4 = *(const float4*)&sA[kk][ty << 2];
            float av[4] = {a4.x, a4.y, a4.z, a4.w};
#pragma unroll
            for (int n4 = 0; n4 < 4; ++n4) {
                float4 b4 = *(const float4*)&sB[kk][(n4 << 6) + (tx << 2)];
                float bv[4] = {b4.x, b4.y, b4.z, b4.w};
#pragma unroll
                for (int m = 0; m < 4; ++m)
#pragma unroll
                    for (int c = 0; c < 4; ++c)
                        acc[m][(n4 << 2) + c] = fmaf(av[m], bv[c], acc[m][(n4 << 2) + c]);
            }
        }
    }
#pragma unroll
    for (int n4 = 0; n4 < 4; ++n4)
#pragma unroll
        for (int c = 0; c < 4; ++c) {
            int h = (n4 << 6) + (tx << 2) + c;
#pragma unroll
            for (int m = 0; m < 4; ++m)
                atomicAdd(&h_acc[(size_t)((a << 6) + (ty << 2) + m) * HH + h],
                          acc[m][(n4 << 2) + c]);
        }
}

// -------- Kernel 4b: relu + second dot for p2p logits ----------
// grid 1024, block 256 (one wave per output row)
__global__ __launch_bounds__(256) void k4b_final(
    const float* __restrict__ h_acc, const float* __restrict__ b1b,
    const float* __restrict__ w2b, const float* __restrict__ b2b,
    float* __restrict__ out)
{
    const int row = blockIdx.x * 4 + (threadIdx.x >> 6);
    const int lane = threadIdx.x & 63;
    float s = 0.f;
#pragma unroll
    for (int p = 0; p < 4; ++p) {
        int h = lane + (p << 6);
        float x = h_acc[(size_t)row * HH + h] + b1b[h];
        s += fmaxf(x, 0.f) * w2b[h];
    }
    for (int off = 1; off < 64; off <<= 1) s += __shfl_xor(s, off);
    if (lane == 0) out[16384 + row] = s + b2b[0];   // output 1: p2p_logits
}

extern "C" void kernel_launch(void* const* d_in, const int* in_sizes, int n_in,
                              void* d_out, int out_size, void* d_ws, size_t ws_size,
                              hipStream_t stream) {
    const float* obj  = (const float*)d_in[0];
    const float* geo  = (const float*)d_in[1];
    const float* mask = (const float*)d_in[2];
    const float* w1a  = (const float*)d_in[3];
    const float* b1a  = (const float*)d_in[4];
    const float* w2a  = (const float*)d_in[5];
    const float* b2a  = (const float*)d_in[6];
    const float* w1b  = (const float*)d_in[7];
    const float* b1b  = (const float*)d_in[8];
    const float* w2b  = (const float*)d_in[9];
    const float* b2b  = (const float*)d_in[10];
    float* out = (float*)d_out;

    char* ws = (char*)d_ws;
    float* ws_logits = (float*)(ws + WS_LOGITS_OFF);
    int*   ws_topk   = (int*)  (ws + WS_TOPK_OFF);
    float* ws_pf     = (float*)(ws + WS_PF_OFF);
    float* ws_h      = (float*)(ws + WS_H_OFF);

    hipMemsetAsync(ws_logits, 0, 16384 * sizeof(float), stream);
    hipMemsetAsync(ws_h, 0, 4096 * 256 * sizeof(float), stream);

    k1_pair_mlp<<<dim3(NN / MT, NN, RR), 256, 0, stream>>>(obj, geo, w1a, b1a, w2a, ws_logits);
    k2_topk<<<1, 1024, 0, stream>>>(ws_logits, mask, b2a, out, ws_topk);
    k3_gather<<<KTOP, 256, 0, stream>>>(obj, geo, ws_topk, ws_pf);
    k4_p2p_mlp<<<dim3(4, KTOP), 256, 0, stream>>>(ws_pf, w1b, ws_h);
    k4b_final<<<KTOP * KTOP / 4, 256, 0, stream>>>(ws_h, b1b, w2b, b2b, out);
}

// Round 2
// 809.726 us; speedup vs baseline: 1.2175x; 1.2175x over previous
//
#include <hip/hip_runtime.h>
#include <math.h>

typedef unsigned int u32;
typedef unsigned short u16;
typedef short bf16x8 __attribute__((ext_vector_type(8)));
typedef float f32x4 __attribute__((ext_vector_type(4)));

#define RR 8
#define NN 128
#define DD 512
#define HH 256
#define KTOP 64
#define NCAND 96

// ws layout (bytes)
#define WS_LOGITS_OFF 0         // 16384 f32
#define WS_CAND_OFF   65536     // 96 i32
#define WS_EXACT_OFF  66048     // 96 f32
#define WS_TOPK_OFF   66560     // 64 i32
#define WS_PF_OFF     66816     // 64*512 f32
#define WS_WH_OFF     197888    // 512*256 u16 (bf16-hi of W1a, chunk-transposed)
#define WS_WL_OFF     460032    // 512*256 u16 (bf16-lo)

__device__ __forceinline__ u16 bf16rne(float x) {
    union { float f; u32 u; } v; v.f = x;
    u32 r = (v.u + 0x7fffu + ((v.u >> 16) & 1u)) >> 16;
    return (u16)r;
}
__device__ __forceinline__ float bf16tof(u16 h) {
    union { float f; u32 u; } v; v.u = ((u32)h) << 16; return v.f;
}

// -------- Kernel 0: split W1a into bf16 hi/lo, layout [kc][h][kk] (kk in [0,32)) ----
__global__ __launch_bounds__(256) void k0_splitW(const float* __restrict__ W1,
                                                 u16* __restrict__ wh, u16* __restrict__ wl)
{
    const int kc = blockIdx.x;      // 16 chunks of K=32
    const int h  = threadIdx.x;     // 256
    u16 rh[32], rl[32];
#pragma unroll
    for (int kk = 0; kk < 32; ++kk) {
        float a = W1[(size_t)(kc * 32 + kk) * HH + h];
        u16 hi = bf16rne(a);
        float lo = a - bf16tof(hi);
        rh[kk] = hi; rl[kk] = bf16rne(lo);
    }
    const size_t base = (size_t)kc * 8192 + (size_t)h * 32;
#pragma unroll
    for (int q = 0; q < 4; ++q) {
        uint4 ph, pl;
        ph.x = (u32)rh[q*8+0] | ((u32)rh[q*8+1] << 16);
        ph.y = (u32)rh[q*8+2] | ((u32)rh[q*8+3] << 16);
        ph.z = (u32)rh[q*8+4] | ((u32)rh[q*8+5] << 16);
        ph.w = (u32)rh[q*8+6] | ((u32)rh[q*8+7] << 16);
        pl.x = (u32)rl[q*8+0] | ((u32)rl[q*8+1] << 16);
        pl.y = (u32)rl[q*8+2] | ((u32)rl[q*8+3] << 16);
        pl.z = (u32)rl[q*8+4] | ((u32)rl[q*8+5] << 16);
        pl.w = (u32)rl[q*8+6] | ((u32)rl[q*8+7] << 16);
        *(uint4*)&wh[base + q*8] = ph;
        *(uint4*)&wl[base + q*8] = pl;
    }
}

// -------- Kernel 1: first-MLP logits via split-bf16 MFMA, accumulate over r ----
// grid (2, 128, 8), block 256 (4 waves). Block tile: M=64(j) x N=256(h), K=512.
// Wave w owns h-slice [w*64, w*64+64). 16x16x32 bf16 MFMA, 3 terms (hh, hl, lh).
__global__ __launch_bounds__(256, 2) void k1_pair_mfma(
    const float* __restrict__ obj, const float* __restrict__ geo,
    const u16* __restrict__ wh, const u16* __restrict__ wl,
    const float* __restrict__ b1, const float* __restrict__ w2,
    float* __restrict__ logits_acc)
{
    const int jb = blockIdx.x, i = blockIdx.y, r = blockIdx.z;
    const int j0 = jb * 64;
    const int tid = threadIdx.x;
    const int lane = tid & 63, wv = tid >> 6;
    const int l15 = lane & 15, quad = lane >> 4;

    __shared__ float sObjI[DD];
    __shared__ __align__(16) u16 sAh[64 * 32], sAl[64 * 32];
    __shared__ __align__(16) u16 sBh[256 * 32], sBl[256 * 32];

    const float* objI = obj + (size_t)(r * NN + i) * DD;
    for (int t = tid; t < DD; t += 256) sObjI[t] = objI[t];

    f32x4 acc[4][4];
#pragma unroll
    for (int mt = 0; mt < 4; ++mt)
#pragma unroll
        for (int nt = 0; nt < 4; ++nt) acc[mt][nt] = (f32x4){0.f, 0.f, 0.f, 0.f};

    const float* geoB = geo + ((size_t)(r * NN + i) * NN + j0) * DD;
    const float* objJ = obj + (size_t)(r * NN + j0) * DD;

    const int aj = tid >> 2;            // j row this thread generates (0..63)
    const int ak = (tid & 3) * 8;       // k offset within chunk (0,8,16,24)

    for (int kc = 0; kc < 16; ++kc) {
        const int k0 = kc * 32;
        __syncthreads();
        // ---- stage split-W1 chunk via global_load_lds (16 B/lane, lane-linear) ----
        {
            const char* gh = (const char*)(wh + (size_t)kc * 8192);
            const char* gl = (const char*)(wl + (size_t)kc * 8192);
#pragma unroll
            for (int p = 0; p < 4; ++p) {
                const int off = (wv * 4 + p) * 1024;   // bytes; wave-uniform
                __builtin_amdgcn_global_load_lds(
                    (const __attribute__((address_space(1))) u32*)(gh + off + lane * 16),
                    (__attribute__((address_space(3))) u32*)((char*)sBh + off), 16, 0, 0);
                __builtin_amdgcn_global_load_lds(
                    (const __attribute__((address_space(1))) u32*)(gl + off + lane * 16),
                    (__attribute__((address_space(3))) u32*)((char*)sBl + off), 16, 0, 0);
            }
        }
        // ---- generate A chunk (obj2obj), split hi/lo, store [j][kk] ----
        {
            float4 g0 = *(const float4*)(geoB + (size_t)aj * DD + k0 + ak);
            float4 g1 = *(const float4*)(geoB + (size_t)aj * DD + k0 + ak + 4);
            float4 o0 = *(const float4*)(objJ + (size_t)aj * DD + k0 + ak);
            float4 o1 = *(const float4*)(objJ + (size_t)aj * DD + k0 + ak + 4);
            float a[8];
            a[0] = fmaf(sObjI[k0+ak+0], o0.x, g0.x);
            a[1] = fmaf(sObjI[k0+ak+1], o0.y, g0.y);
            a[2] = fmaf(sObjI[k0+ak+2], o0.z, g0.z);
            a[3] = fmaf(sObjI[k0+ak+3], o0.w, g0.w);
            a[4] = fmaf(sObjI[k0+ak+4], o1.x, g1.x);
            a[5] = fmaf(sObjI[k0+ak+5], o1.y, g1.y);
            a[6] = fmaf(sObjI[k0+ak+6], o1.z, g1.z);
            a[7] = fmaf(sObjI[k0+ak+7], o1.w, g1.w);
            u16 hs[8], ls[8];
#pragma unroll
            for (int q = 0; q < 8; ++q) {
                hs[q] = bf16rne(a[q]);
                ls[q] = bf16rne(a[q] - bf16tof(hs[q]));
            }
            uint4 ph, pl;
            ph.x = (u32)hs[0] | ((u32)hs[1] << 16); ph.y = (u32)hs[2] | ((u32)hs[3] << 16);
            ph.z = (u32)hs[4] | ((u32)hs[5] << 16); ph.w = (u32)hs[6] | ((u32)hs[7] << 16);
            pl.x = (u32)ls[0] | ((u32)ls[1] << 16); pl.y = (u32)ls[2] | ((u32)ls[3] << 16);
            pl.z = (u32)ls[4] | ((u32)ls[5] << 16); pl.w = (u32)ls[6] | ((u32)ls[7] << 16);
            *(uint4*)&sAh[aj * 32 + ak] = ph;
            *(uint4*)&sAl[aj * 32 + ak] = pl;
        }
        __syncthreads();
        // ---- fragment loads + 48 MFMA ----
        bf16x8 Bh[4], Bl[4], Ah[4], Al[4];
#pragma unroll
        for (int nt = 0; nt < 4; ++nt) {
            const int row = wv * 64 + nt * 16 + l15;
            Bh[nt] = *(const bf16x8*)&sBh[row * 32 + quad * 8];
            Bl[nt] = *(const bf16x8*)&sBl[row * 32 + quad * 8];
        }
#pragma unroll
        for (int mt = 0; mt < 4; ++mt) {
            const int row = mt * 16 + l15;
            Ah[mt] = *(const bf16x8*)&sAh[row * 32 + quad * 8];
            Al[mt] = *(const bf16x8*)&sAl[row * 32 + quad * 8];
        }
#pragma unroll
        for (int mt = 0; mt < 4; ++mt)
#pragma unroll
            for (int nt = 0; nt < 4; ++nt) {
                acc[mt][nt] = __builtin_amdgcn_mfma_f32_16x16x32_bf16(Ah[mt], Bh[nt], acc[mt][nt], 0, 0, 0);
                acc[mt][nt] = __builtin_amdgcn_mfma_f32_16x16x32_bf16(Ah[mt], Bl[nt], acc[mt][nt], 0, 0, 0);
                acc[mt][nt] = __builtin_amdgcn_mfma_f32_16x16x32_bf16(Al[mt], Bh[nt], acc[mt][nt], 0, 0, 0);
            }
    }
    // ---- epilogue: relu(C+b1)·w2 reduced over h, atomic-accumulate over r & waves ----
    float pr[4][4];
#pragma unroll
    for (int mt = 0; mt < 4; ++mt)
#pragma unroll
        for (int t = 0; t < 4; ++t) pr[mt][t] = 0.f;
#pragma unroll
    for (int nt = 0; nt < 4; ++nt) {
        const int h = wv * 64 + nt * 16 + l15;
        const float bb = b1[h], w = w2[h];
#pragma unroll
        for (int mt = 0; mt < 4; ++mt)
#pragma unroll
            for (int t = 0; t < 4; ++t)
                pr[mt][t] += fmaxf(acc[mt][nt][t] + bb, 0.f) * w;
    }
#pragma unroll
    for (int mt = 0; mt < 4; ++mt)
#pragma unroll
        for (int t = 0; t < 4; ++t) {
            float v = pr[mt][t];
            v += __shfl_xor(v, 1); v += __shfl_xor(v, 2);
            v += __shfl_xor(v, 4); v += __shfl_xor(v, 8);
            if (l15 == 0)
                atomicAdd(&logits_acc[i * NN + j0 + mt * 16 + quad * 4 + t], v);
        }
}

// -------- Kernel 2: finalize o2o logits (out0) + approximate top-96 superset ----
__global__ __launch_bounds__(256) void k2_select(
    const float* __restrict__ logits_acc, const float* __restrict__ mask,
    const float* __restrict__ b2a, float* __restrict__ out, int* __restrict__ cand)
{
    __shared__ float sP[16384];
    __shared__ float sVal[4];
    __shared__ int sIdx[4];
    __shared__ int sWin;
    const int t = threadIdx.x;
    const float bias = b2a[0];
    for (int e = 0; e < 64; ++e) {
        const int idx = e * 256 + t;
        const float lg = logits_acc[idx] * 0.125f + bias;
        out[idx] = lg;                                    // output 0
        sP[idx] = (1.f / (1.f + expf(-lg))) * mask[idx];  // approx pair_probs
    }
    __syncthreads();
    float lv = -1.f; int li = 1 << 30;
    for (int e = 0; e < 64; ++e) {
        const int idx = e * 256 + t;
        const float v = sP[idx];
        if (v > lv) { lv = v; li = idx; }
    }
    const int lane = t & 63, wvv = t >> 6;
    for (int it = 0; it < NCAND; ++it) {
        float bv = lv; int bi = li;
#pragma unroll
        for (int off = 1; off < 64; off <<= 1) {
            const float ov = __shfl_xor(bv, off);
            const int   oi = __shfl_xor(bi, off);
            if (ov > bv || (ov == bv && oi < bi)) { bv = ov; bi = oi; }
        }
        if (lane == 0) { sVal[wvv] = bv; sIdx[wvv] = bi; }
        __syncthreads();
        if (t == 0) {
            float B = -2.f; int I = 1 << 30;
            for (int w = 0; w < 4; ++w)
                if (sVal[w] > B || (sVal[w] == B && sIdx[w] < I)) { B = sVal[w]; I = sIdx[w]; }
            sWin = I; cand[it] = I;
        }
        __syncthreads();
        const int I = sWin;
        if ((I & 255) == t) {         // owner consumes + rebuilds local argmax
            sP[I] = -1.f;
            lv = -1.f; li = 1 << 30;
            for (int e = 0; e < 64; ++e) {
                const int idx = e * 256 + t;
                const float v = sP[idx];
                if (v > lv) { lv = v; li = idx; }
            }
        }
    }
}

// -------- Kernel 5: exact fp32 recompute of the 96 candidate logits ----
__global__ __launch_bounds__(256) void k5_exact(
    const float* __restrict__ obj, const float* __restrict__ geo,
    const float* __restrict__ W1, const float* __restrict__ b1,
    const float* __restrict__ w2, const float* __restrict__ b2a,
    const int* __restrict__ cand, float* __restrict__ exact)
{
    const int c = blockIdx.x;
    const int idx = cand[c];
    const int i = idx >> 7, j = idx & 127;
    const int t = threadIdx.x;
    __shared__ float sA[RR][DD];
    __shared__ float sRed[4];
    for (int f = t; f < RR * DD; f += 256) {
        const int r = f >> 9, k = f & 511;
        sA[r][k] = fmaf(obj[(size_t)(r * NN + i) * DD + k],
                        obj[(size_t)(r * NN + j) * DD + k],
                        geo[((size_t)(r * NN + i) * NN + j) * DD + k]);
    }
    __syncthreads();
    float hv[RR];
#pragma unroll
    for (int r = 0; r < RR; ++r) hv[r] = 0.f;
#pragma unroll 4
    for (int k = 0; k < DD; ++k) {
        const float w = W1[(size_t)k * HH + t];
#pragma unroll
        for (int r = 0; r < RR; ++r) hv[r] = fmaf(sA[r][k], w, hv[r]);
    }
    const float bb = b1[t], wv2 = w2[t];
    float p = 0.f;
#pragma unroll
    for (int r = 0; r < RR; ++r) p += fmaxf(hv[r] + bb, 0.f) * wv2;
#pragma unroll
    for (int off = 1; off < 64; off <<= 1) p += __shfl_xor(p, off);
    if ((t & 63) == 0) sRed[t >> 6] = p;
    __syncthreads();
    if (t == 0) exact[c] = (sRed[0] + sRed[1] + sRed[2] + sRed[3]) * 0.125f + b2a[0];
}

// -------- Kernel 2b: exact re-rank of 96 candidates -> final top-64 (out2) ----
__global__ __launch_bounds__(64) void k2b_rank(
    const float* __restrict__ exact, const int* __restrict__ cand,
    float* __restrict__ out, int* __restrict__ topk)
{
    const int l = threadIdx.x;  // 64
    float v0 = 1.f / (1.f + expf(-exact[l]));
    int   i0 = cand[l];
    float v1 = -1.f; int i1 = (1 << 30) + 1;
    if (l < NCAND - 64) { v1 = 1.f / (1.f + expf(-exact[l + 64])); i1 = cand[l + 64]; }
    for (int it = 0; it < KTOP; ++it) {
        float bv; int bi;
        if (v0 > v1 || (v0 == v1 && i0 < i1)) { bv = v0; bi = i0; } else { bv = v1; bi = i1; }
#pragma unroll
        for (int off = 1; off < 64; off <<= 1) {
            const float ov = __shfl_xor(bv, off);
            const int   oi = __shfl_xor(bi, off);
            if (ov > bv || (ov == bv && oi < bi)) { bv = ov; bi = oi; }
        }
        if (l == 0) { topk[it] = bi; out[20480 + it] = (float)bi; }
        if (i0 == bi) v0 = -2.f;
        if (i1 == bi) v1 = -2.f;
    }
}

// -------- Kernel 3: gather averaged pair features for final top-64 ----
__global__ __launch_bounds__(256) void k3_gather(
    const float* __restrict__ obj, const float* __restrict__ geo,
    const int* __restrict__ ws_topk, float* __restrict__ pf)
{
    const int tix = blockIdx.x;            // 0..63
    const int idx = ws_topk[tix];
    const int i = idx >> 7, j = idx & 127;
    for (int dd = threadIdx.x; dd < DD; dd += 256) {
        float s = 0.f;
#pragma unroll
        for (int r = 0; r < RR; ++r) {
            const float oi = obj[(size_t)(r * NN + i) * DD + dd];
            const float oj = obj[(size_t)(r * NN + j) * DD + dd];
            const float g  = geo[((size_t)(r * NN + i) * NN + j) * DD + dd];
            s += oi * oj + g;
        }
        pf[tix * DD + dd] = s * 0.125f;
    }
}

// -------- Kernel 4: fused p2p MLP, one block per row a, full K, direct write ----
__global__ __launch_bounds__(256) void k4_p2p(
    const float* __restrict__ pf, const float* __restrict__ W1,
    const float* __restrict__ b1, const float* __restrict__ w2,
    const float* __restrict__ b2, float* __restrict__ out)
{
    const int a = blockIdx.x;
    const int tid = threadIdx.x;
    const int tx = tid & 15, ty = tid >> 4;

    __shared__ float sPfA[DD];
    __shared__ __align__(16) float sA[32][68];
    __shared__ __align__(16) float sB[32][HH];

    const float* pfA = pf + (size_t)a * DD;
    for (int t = tid; t < DD; t += 256) sPfA[t] = pfA[t];

    float acc[4][16];
#pragma unroll
    for (int m = 0; m < 4; ++m)
#pragma unroll
        for (int n = 0; n < 16; ++n) acc[m][n] = 0.f;

    for (int kc = 0; kc < 16; ++kc) {
        const int k0 = kc * 32;
        __syncthreads();
#pragma unroll
        for (int p = 0; p < 8; ++p) {
            const int f = tid + p * 256;
            const int kk = f >> 6, c = (f & 63) << 2;
            *(float4*)&sB[kk][c] = *(const float4*)&W1[(size_t)(k0 + kk) * HH + c];
        }
#pragma unroll
        for (int p = 0; p < 2; ++p) {
            const int f = tid + p * 256;
            const int j = f >> 3, kk = (f & 7) << 2;
            float4 o = *(const float4*)(pf + (size_t)j * DD + k0 + kk);
            sA[kk + 0][j] = sPfA[k0 + kk + 0] * o.x;
            sA[kk + 1][j] = sPfA[k0 + kk + 1] * o.y;
            sA[kk + 2][j] = sPfA[k0 + kk + 2] * o.z;
            sA[kk + 3][j] = sPfA[k0 + kk + 3] * o.w;
        }
        __syncthreads();
#pragma unroll 8
        for (int kk = 0; kk < 32; ++kk) {
            float4 a4 = *(const float4*)&sA[kk][ty << 2];
            float av[4] = {a4.x, a4.y, a4.z, a4.w};
#pragma unroll
            for (int n4 = 0; n4 < 4; ++n4) {
                float4 b4 = *(const float4*)&sB[kk][(n4 << 6) + (tx << 2)];
                float bv[4] = {b4.x, b4.y, b4.z, b4.w};
#pragma unroll
                for (int m = 0; m < 4; ++m)
#pragma unroll
                    for (int c = 0; c < 4; ++c)
                        acc[m][(n4 << 2) + c] = fmaf(av[m], bv[c], acc[m][(n4 << 2) + c]);
            }
        }
    }
    const float b20 = b2[0];
    float pr[4] = {0.f, 0.f, 0.f, 0.f};
#pragma unroll
    for (int n4 = 0; n4 < 4; ++n4)
#pragma unroll
        for (int c = 0; c < 4; ++c) {
            const int h = (n4 << 6) + (tx << 2) + c;
            const float bb = b1[h], w = w2[h];
#pragma unroll
            for (int m = 0; m < 4; ++m)
                pr[m] += fmaxf(acc[m][(n4 << 2) + c] + bb, 0.f) * w;
        }
#pragma unroll
    for (int m = 0; m < 4; ++m) {
        pr[m] += __shfl_xor(pr[m], 1); pr[m] += __shfl_xor(pr[m], 2);
        pr[m] += __shfl_xor(pr[m], 4); pr[m] += __shfl_xor(pr[m], 8);
        if (tx == 0)
            out[16384 + a * 64 + (ty << 2) + m] = pr[m] + b20;  // output 1
    }
}

extern "C" void kernel_launch(void* const* d_in, const int* in_sizes, int n_in,
                              void* d_out, int out_size, void* d_ws, size_t ws_size,
                              hipStream_t stream) {
    const float* obj  = (const float*)d_in[0];
    const float* geo  = (const float*)d_in[1];
    const float* mask = (const float*)d_in[2];
    const float* w1a  = (const float*)d_in[3];
    const float* b1a  = (const float*)d_in[4];
    const float* w2a  = (const float*)d_in[5];
    const float* b2a  = (const float*)d_in[6];
    const float* w1b  = (const float*)d_in[7];
    const float* b1b  = (const float*)d_in[8];
    const float* w2b  = (const float*)d_in[9];
    const float* b2b  = (const float*)d_in[10];
    float* out = (float*)d_out;

    char* ws = (char*)d_ws;
    float* ws_logits = (float*)(ws + WS_LOGITS_OFF);
    int*   ws_cand   = (int*)  (ws + WS_CAND_OFF);
    float* ws_exact  = (float*)(ws + WS_EXACT_OFF);
    int*   ws_topk   = (int*)  (ws + WS_TOPK_OFF);
    float* ws_pf     = (float*)(ws + WS_PF_OFF);
    u16*   ws_wh     = (u16*)  (ws + WS_WH_OFF);
    u16*   ws_wl     = (u16*)  (ws + WS_WL_OFF);

    hipMemsetAsync(ws_logits, 0, 16384 * sizeof(float), stream);

    k0_splitW<<<16, 256, 0, stream>>>(w1a, ws_wh, ws_wl);
    k1_pair_mfma<<<dim3(2, NN, RR), 256, 0, stream>>>(obj, geo, ws_wh, ws_wl, b1a, w2a, ws_logits);
    k2_select<<<1, 256, 0, stream>>>(ws_logits, mask, b2a, out, ws_cand);
    k5_exact<<<NCAND, 256, 0, stream>>>(obj, geo, w1a, b1a, w2a, b2a, ws_cand, ws_exact);
    k2b_rank<<<1, 64, 0, stream>>>(ws_exact, ws_cand, out, ws_topk);
    k3_gather<<<KTOP, 256, 0, stream>>>(obj, geo, ws_topk, ws_pf);
    k4_p2p<<<KTOP, 256, 0, stream>>>(ws_pf, w1b, b1b, w2b, b2b, out);
}

// Round 3
// 634.891 us; speedup vs baseline: 1.5528x; 1.2754x over previous
//
#include <hip/hip_runtime.h>
#include <math.h>

typedef unsigned int u32;
typedef unsigned long long u64;
typedef unsigned short u16;
typedef short bf16x8 __attribute__((ext_vector_type(8)));
typedef float f32x4 __attribute__((ext_vector_type(4)));

#define RR 8
#define NN 128
#define DD 512
#define HH 256
#define KTOP 64
#define NCAND 256    // candidate buffer size
#define NSEL 128     // min candidates selected by threshold

// ws layout (bytes)
#define WS_LOGITS_OFF 0         // 16384 f32
#define WS_CAND_OFF   65536     // 256 i32
#define WS_EXACT_OFF  66560     // 256 f32
#define WS_CNT_OFF    67584     // 1 i32 (+pad)
#define WS_TOPK_OFF   67600     // 64 i32
#define WS_PF_OFF     67856     // 64*512 f32
#define WS_WH_OFF     198928    // 512*256 u16 (bf16-hi of W1a, chunk-transposed)
#define WS_WL_OFF     461072    // 512*256 u16 (bf16-lo)

__device__ __forceinline__ u16 bf16rne(float x) {
    union { float f; u32 u; } v; v.f = x;
    u32 r = (v.u + 0x7fffu + ((v.u >> 16) & 1u)) >> 16;
    return (u16)r;
}
__device__ __forceinline__ float bf16tof(u16 h) {
    union { float f; u32 u; } v; v.u = ((u32)h) << 16; return v.f;
}
__device__ __forceinline__ u32 f32sort(float x) {
    union { float f; u32 u; } v; v.f = x;
    return v.u ^ ((v.u & 0x80000000u) ? 0xFFFFFFFFu : 0x80000000u);
}

// -------- Kernel 0: split W1a into bf16 hi/lo, layout [kc][h][kk] (kk in [0,32)) ----
__global__ __launch_bounds__(256) void k0_splitW(const float* __restrict__ W1,
                                                 u16* __restrict__ wh, u16* __restrict__ wl)
{
    const int kc = blockIdx.x;      // 16 chunks of K=32
    const int h  = threadIdx.x;     // 256
    u16 rh[32], rl[32];
#pragma unroll
    for (int kk = 0; kk < 32; ++kk) {
        float a = W1[(size_t)(kc * 32 + kk) * HH + h];
        u16 hi = bf16rne(a);
        float lo = a - bf16tof(hi);
        rh[kk] = hi; rl[kk] = bf16rne(lo);
    }
    const size_t base = (size_t)kc * 8192 + (size_t)h * 32;
#pragma unroll
    for (int q = 0; q < 4; ++q) {
        uint4 ph, pl;
        ph.x = (u32)rh[q*8+0] | ((u32)rh[q*8+1] << 16);
        ph.y = (u32)rh[q*8+2] | ((u32)rh[q*8+3] << 16);
        ph.z = (u32)rh[q*8+4] | ((u32)rh[q*8+5] << 16);
        ph.w = (u32)rh[q*8+6] | ((u32)rh[q*8+7] << 16);
        pl.x = (u32)rl[q*8+0] | ((u32)rl[q*8+1] << 16);
        pl.y = (u32)rl[q*8+2] | ((u32)rl[q*8+3] << 16);
        pl.z = (u32)rl[q*8+4] | ((u32)rl[q*8+5] << 16);
        pl.w = (u32)rl[q*8+6] | ((u32)rl[q*8+7] << 16);
        *(uint4*)&wh[base + q*8] = ph;
        *(uint4*)&wl[base + q*8] = pl;
    }
}

// -------- Kernel 1: first-MLP logits via split-bf16 MFMA, accumulate over r ----
__global__ __launch_bounds__(256, 2) void k1_pair_mfma(
    const float* __restrict__ obj, const float* __restrict__ geo,
    const u16* __restrict__ wh, const u16* __restrict__ wl,
    const float* __restrict__ b1, const float* __restrict__ w2,
    float* __restrict__ logits_acc)
{
    const int jb = blockIdx.x, i = blockIdx.y, r = blockIdx.z;
    const int j0 = jb * 64;
    const int tid = threadIdx.x;
    const int lane = tid & 63, wv = tid >> 6;
    const int l15 = lane & 15, quad = lane >> 4;

    __shared__ float sObjI[DD];
    __shared__ __align__(16) u16 sAh[64 * 32], sAl[64 * 32];
    __shared__ __align__(16) u16 sBh[256 * 32], sBl[256 * 32];

    const float* objI = obj + (size_t)(r * NN + i) * DD;
    for (int t = tid; t < DD; t += 256) sObjI[t] = objI[t];

    f32x4 acc[4][4];
#pragma unroll
    for (int mt = 0; mt < 4; ++mt)
#pragma unroll
        for (int nt = 0; nt < 4; ++nt) acc[mt][nt] = (f32x4){0.f, 0.f, 0.f, 0.f};

    const float* geoB = geo + ((size_t)(r * NN + i) * NN + j0) * DD;
    const float* objJ = obj + (size_t)(r * NN + j0) * DD;

    const int aj = tid >> 2;            // j row this thread generates (0..63)
    const int ak = (tid & 3) * 8;       // k offset within chunk (0,8,16,24)

    for (int kc = 0; kc < 16; ++kc) {
        const int k0 = kc * 32;
        __syncthreads();
        {
            const char* gh = (const char*)(wh + (size_t)kc * 8192);
            const char* gl = (const char*)(wl + (size_t)kc * 8192);
#pragma unroll
            for (int p = 0; p < 4; ++p) {
                const int off = (wv * 4 + p) * 1024;   // bytes; wave-uniform
                __builtin_amdgcn_global_load_lds(
                    (const __attribute__((address_space(1))) u32*)(gh + off + lane * 16),
                    (__attribute__((address_space(3))) u32*)((char*)sBh + off), 16, 0, 0);
                __builtin_amdgcn_global_load_lds(
                    (const __attribute__((address_space(1))) u32*)(gl + off + lane * 16),
                    (__attribute__((address_space(3))) u32*)((char*)sBl + off), 16, 0, 0);
            }
        }
        {
            float4 g0 = *(const float4*)(geoB + (size_t)aj * DD + k0 + ak);
            float4 g1 = *(const float4*)(geoB + (size_t)aj * DD + k0 + ak + 4);
            float4 o0 = *(const float4*)(objJ + (size_t)aj * DD + k0 + ak);
            float4 o1 = *(const float4*)(objJ + (size_t)aj * DD + k0 + ak + 4);
            float a[8];
            a[0] = fmaf(sObjI[k0+ak+0], o0.x, g0.x);
            a[1] = fmaf(sObjI[k0+ak+1], o0.y, g0.y);
            a[2] = fmaf(sObjI[k0+ak+2], o0.z, g0.z);
            a[3] = fmaf(sObjI[k0+ak+3], o0.w, g0.w);
            a[4] = fmaf(sObjI[k0+ak+4], o1.x, g1.x);
            a[5] = fmaf(sObjI[k0+ak+5], o1.y, g1.y);
            a[6] = fmaf(sObjI[k0+ak+6], o1.z, g1.z);
            a[7] = fmaf(sObjI[k0+ak+7], o1.w, g1.w);
            u16 hs[8], ls[8];
#pragma unroll
            for (int q = 0; q < 8; ++q) {
                hs[q] = bf16rne(a[q]);
                ls[q] = bf16rne(a[q] - bf16tof(hs[q]));
            }
            uint4 ph, pl;
            ph.x = (u32)hs[0] | ((u32)hs[1] << 16); ph.y = (u32)hs[2] | ((u32)hs[3] << 16);
            ph.z = (u32)hs[4] | ((u32)hs[5] << 16); ph.w = (u32)hs[6] | ((u32)hs[7] << 16);
            pl.x = (u32)ls[0] | ((u32)ls[1] << 16); pl.y = (u32)ls[2] | ((u32)ls[3] << 16);
            pl.z = (u32)ls[4] | ((u32)ls[5] << 16); pl.w = (u32)ls[6] | ((u32)ls[7] << 16);
            *(uint4*)&sAh[aj * 32 + ak] = ph;
            *(uint4*)&sAl[aj * 32 + ak] = pl;
        }
        __syncthreads();
        bf16x8 Bh[4], Bl[4], Ah[4], Al[4];
#pragma unroll
        for (int nt = 0; nt < 4; ++nt) {
            const int row = wv * 64 + nt * 16 + l15;
            Bh[nt] = *(const bf16x8*)&sBh[row * 32 + quad * 8];
            Bl[nt] = *(const bf16x8*)&sBl[row * 32 + quad * 8];
        }
#pragma unroll
        for (int mt = 0; mt < 4; ++mt) {
            const int row = mt * 16 + l15;
            Ah[mt] = *(const bf16x8*)&sAh[row * 32 + quad * 8];
            Al[mt] = *(const bf16x8*)&sAl[row * 32 + quad * 8];
        }
#pragma unroll
        for (int mt = 0; mt < 4; ++mt)
#pragma unroll
            for (int nt = 0; nt < 4; ++nt) {
                acc[mt][nt] = __builtin_amdgcn_mfma_f32_16x16x32_bf16(Ah[mt], Bh[nt], acc[mt][nt], 0, 0, 0);
                acc[mt][nt] = __builtin_amdgcn_mfma_f32_16x16x32_bf16(Ah[mt], Bl[nt], acc[mt][nt], 0, 0, 0);
                acc[mt][nt] = __builtin_amdgcn_mfma_f32_16x16x32_bf16(Al[mt], Bh[nt], acc[mt][nt], 0, 0, 0);
            }
    }
    float pr[4][4];
#pragma unroll
    for (int mt = 0; mt < 4; ++mt)
#pragma unroll
        for (int t = 0; t < 4; ++t) pr[mt][t] = 0.f;
#pragma unroll
    for (int nt = 0; nt < 4; ++nt) {
        const int h = wv * 64 + nt * 16 + l15;
        const float bb = b1[h], w = w2[h];
#pragma unroll
        for (int mt = 0; mt < 4; ++mt)
#pragma unroll
            for (int t = 0; t < 4; ++t)
                pr[mt][t] += fmaxf(acc[mt][nt][t] + bb, 0.f) * w;
    }
#pragma unroll
    for (int mt = 0; mt < 4; ++mt)
#pragma unroll
        for (int t = 0; t < 4; ++t) {
            float v = pr[mt][t];
            v += __shfl_xor(v, 1); v += __shfl_xor(v, 2);
            v += __shfl_xor(v, 4); v += __shfl_xor(v, 8);
            if (l15 == 0)
                atomicAdd(&logits_acc[i * NN + j0 + mt * 16 + quad * 4 + t], v);
        }
}

// -------- Kernel 2: finalize o2o logits (out0) + radix-threshold candidate select ----
// Selects >=NSEL candidates by approximate logit (sortable-uint, 2-level 8-bit histogram).
__global__ __launch_bounds__(1024) void k2_hist(
    const float* __restrict__ logits_acc, const float* __restrict__ mask,
    const float* __restrict__ b2a, float* __restrict__ out,
    int* __restrict__ cand, int* __restrict__ cnt_out)
{
    __shared__ u32 h1[256], h2[256];
    __shared__ int sB1, sRem, sT16;
    __shared__ u32 sCnt;
    const int t = threadIdx.x;
    if (t < 256) { h1[t] = 0; h2[t] = 0; }
    if (t == 0) sCnt = 0;
    __syncthreads();
    const float bias = b2a[0];
    u32 skey[16];
#pragma unroll
    for (int e = 0; e < 16; ++e) {
        const int idx = e * 1024 + t;
        const float lg = logits_acc[idx] * 0.125f + bias;
        out[idx] = lg;                       // output 0
        u32 s = f32sort(lg);
        if (mask[idx] == 0.f) s = 0;         // excluded (prob forced to 0)
        skey[e] = s;
        atomicAdd(&h1[s >> 24], 1u);
    }
    __syncthreads();
    if (t == 0) {
        u32 cum = 0; int b = 255;
        for (; b > 0; --b) { u32 c = h1[b]; if (cum + c >= (u32)NSEL) break; cum += c; }
        sB1 = b; sRem = NSEL - (int)cum;
    }
    __syncthreads();
    const int B1 = sB1;
#pragma unroll
    for (int e = 0; e < 16; ++e) {
        const u32 s = skey[e];
        if ((int)(s >> 24) == B1) atomicAdd(&h2[(s >> 16) & 0xFF], 1u);
    }
    __syncthreads();
    if (t == 0) {
        const int rem = sRem; u32 cum = 0; int b = 255;
        for (; b > 0; --b) { cum += h2[b]; if ((int)cum >= rem) break; }
        sT16 = (B1 << 8) | b;
    }
    __syncthreads();
    const u32 T16 = (u32)sT16;
#pragma unroll
    for (int e = 0; e < 16; ++e) {
        const u32 s = skey[e];
        if (s != 0 && (s >> 16) >= T16) {
            const u32 pos = atomicAdd(&sCnt, 1u);
            if (pos < (u32)NCAND) cand[pos] = e * 1024 + t;
        }
    }
    __syncthreads();
    if (t == 0) *cnt_out = (int)(sCnt < (u32)NCAND ? sCnt : (u32)NCAND);
}

// -------- Kernel 5: exact fp32 recompute of candidate logits ----
__global__ __launch_bounds__(256) void k5_exact(
    const float* __restrict__ obj, const float* __restrict__ geo,
    const float* __restrict__ W1, const float* __restrict__ b1,
    const float* __restrict__ w2, const float* __restrict__ b2a,
    const int* __restrict__ cand, const int* __restrict__ cnt_ptr,
    float* __restrict__ exact)
{
    const int c = blockIdx.x;
    if (c >= *cnt_ptr) { if (threadIdx.x == 0) exact[c] = -1e30f; return; }
    const int idx = cand[c];
    const int i = idx >> 7, j = idx & 127;
    const int t = threadIdx.x;
    __shared__ float sA[RR][DD];
    __shared__ float sRed[4];
    for (int f = t; f < RR * DD; f += 256) {
        const int r = f >> 9, k = f & 511;
        sA[r][k] = fmaf(obj[(size_t)(r * NN + i) * DD + k],
                        obj[(size_t)(r * NN + j) * DD + k],
                        geo[((size_t)(r * NN + i) * NN + j) * DD + k]);
    }
    __syncthreads();
    float hv[RR];
#pragma unroll
    for (int r = 0; r < RR; ++r) hv[r] = 0.f;
#pragma unroll 4
    for (int k = 0; k < DD; ++k) {
        const float w = W1[(size_t)k * HH + t];
#pragma unroll
        for (int r = 0; r < RR; ++r) hv[r] = fmaf(sA[r][k], w, hv[r]);
    }
    const float bb = b1[t], wv2 = w2[t];
    float p = 0.f;
#pragma unroll
    for (int r = 0; r < RR; ++r) p += fmaxf(hv[r] + bb, 0.f) * wv2;
#pragma unroll
    for (int off = 1; off < 64; off <<= 1) p += __shfl_xor(p, off);
    if ((t & 63) == 0) sRed[t >> 6] = p;
    __syncthreads();
    if (t == 0) exact[c] = (sRed[0] + sRed[1] + sRed[2] + sRed[3]) * 0.125f + b2a[0];
}

// -------- Kernel 2b: bitonic re-rank of candidates by exact prob -> top-64 (out2) ----
__global__ __launch_bounds__(256) void k_sort(
    const float* __restrict__ exact, const int* __restrict__ cand,
    float* __restrict__ out, int* __restrict__ topk)
{
    __shared__ u64 sKey[NCAND];
    const int t = threadIdx.x;
    {
        const float lg = exact[t];
        u32 ps = 0; u32 idx = 0x7FFFFFFFu;
        if (lg > -1e29f) {
            const float p = 1.f / (1.f + expf(-lg));   // same formula as passing R2 ranker
            ps = f32sort(p);
            idx = (u32)cand[t];
        }
        sKey[t] = ((u64)ps << 32) | (u64)(0xFFFFFFFFu - idx);
    }
    for (int k = 2; k <= NCAND; k <<= 1)
        for (int j = k >> 1; j > 0; j >>= 1) {
            __syncthreads();
            const int ixj = t ^ j;
            if (ixj > t) {
                const u64 a = sKey[t], b = sKey[ixj];
                if (((t & k) == 0) ? (a < b) : (a > b)) { sKey[t] = b; sKey[ixj] = a; }
            }
        }
    __syncthreads();
    if (t < KTOP) {
        const u32 idx = 0xFFFFFFFFu - (u32)(sKey[t] & 0xFFFFFFFFull);
        topk[t] = (int)idx;
        out[20480 + t] = (float)idx;      // output 2
    }
}

// -------- Kernel 3: gather averaged pair features for final top-64 ----
__global__ __launch_bounds__(256) void k3_gather(
    const float* __restrict__ obj, const float* __restrict__ geo,
    const int* __restrict__ ws_topk, float* __restrict__ pf)
{
    const int tix = blockIdx.x;            // 0..63
    const int idx = ws_topk[tix];
    const int i = idx >> 7, j = idx & 127;
    for (int dd = threadIdx.x; dd < DD; dd += 256) {
        float s = 0.f;
#pragma unroll
        for (int r = 0; r < RR; ++r) {
            const float oi = obj[(size_t)(r * NN + i) * DD + dd];
            const float oj = obj[(size_t)(r * NN + j) * DD + dd];
            const float g  = geo[((size_t)(r * NN + i) * NN + j) * DD + dd];
            s += oi * oj + g;
        }
        pf[tix * DD + dd] = s * 0.125f;
    }
}

// -------- Kernel 4: fused p2p MLP, one block per row a, full K, direct write ----
__global__ __launch_bounds__(256) void k4_p2p(
    const float* __restrict__ pf, const float* __restrict__ W1,
    const float* __restrict__ b1, const float* __restrict__ w2,
    const float* __restrict__ b2, float* __restrict__ out)
{
    const int a = blockIdx.x;
    const int tid = threadIdx.x;
    const int tx = tid & 15, ty = tid >> 4;

    __shared__ float sPfA[DD];
    __shared__ __align__(16) float sA[32][68];
    __shared__ __align__(16) float sB[32][HH];

    const float* pfA = pf + (size_t)a * DD;
    for (int t = tid; t < DD; t += 256) sPfA[t] = pfA[t];

    float acc[4][16];
#pragma unroll
    for (int m = 0; m < 4; ++m)
#pragma unroll
        for (int n = 0; n < 16; ++n) acc[m][n] = 0.f;

    for (int kc = 0; kc < 16; ++kc) {
        const int k0 = kc * 32;
        __syncthreads();
#pragma unroll
        for (int p = 0; p < 8; ++p) {
            const int f = tid + p * 256;
            const int kk = f >> 6, c = (f & 63) << 2;
            *(float4*)&sB[kk][c] = *(const float4*)&W1[(size_t)(k0 + kk) * HH + c];
        }
#pragma unroll
        for (int p = 0; p < 2; ++p) {
            const int f = tid + p * 256;
            const int j = f >> 3, kk = (f & 7) << 2;
            float4 o = *(const float4*)(pf + (size_t)j * DD + k0 + kk);
            sA[kk + 0][j] = sPfA[k0 + kk + 0] * o.x;
            sA[kk + 1][j] = sPfA[k0 + kk + 1] * o.y;
            sA[kk + 2][j] = sPfA[k0 + kk + 2] * o.z;
            sA[kk + 3][j] = sPfA[k0 + kk + 3] * o.w;
        }
        __syncthreads();
#pragma unroll 8
        for (int kk = 0; kk < 32; ++kk) {
            float4 a4 = *(const float4*)&sA[kk][ty << 2];
            float av[4] = {a4.x, a4.y, a4.z, a4.w};
#pragma unroll
            for (int n4 = 0; n4 < 4; ++n4) {
                float4 b4 = *(const float4*)&sB[kk][(n4 << 6) + (tx << 2)];
                float bv[4] = {b4.x, b4.y, b4.z, b4.w};
#pragma unroll
                for (int m = 0; m < 4; ++m)
#pragma unroll
                    for (int c = 0; c < 4; ++c)
                        acc[m][(n4 << 2) + c] = fmaf(av[m], bv[c], acc[m][(n4 << 2) + c]);
            }
        }
    }
    const float b20 = b2[0];
    float pr[4] = {0.f, 0.f, 0.f, 0.f};
#pragma unroll
    for (int n4 = 0; n4 < 4; ++n4)
#pragma unroll
        for (int c = 0; c < 4; ++c) {
            const int h = (n4 << 6) + (tx << 2) + c;
            const float bb = b1[h], w = w2[h];
#pragma unroll
            for (int m = 0; m < 4; ++m)
                pr[m] += fmaxf(acc[m][(n4 << 2) + c] + bb, 0.f) * w;
        }
#pragma unroll
    for (int m = 0; m < 4; ++m) {
        pr[m] += __shfl_xor(pr[m], 1); pr[m] += __shfl_xor(pr[m], 2);
        pr[m] += __shfl_xor(pr[m], 4); pr[m] += __shfl_xor(pr[m], 8);
        if (tx == 0)
            out[16384 + a * 64 + (ty << 2) + m] = pr[m] + b20;  // output 1
    }
}

extern "C" void kernel_launch(void* const* d_in, const int* in_sizes, int n_in,
                              void* d_out, int out_size, void* d_ws, size_t ws_size,
                              hipStream_t stream) {
    const float* obj  = (const float*)d_in[0];
    const float* geo  = (const float*)d_in[1];
    const float* mask = (const float*)d_in[2];
    const float* w1a  = (const float*)d_in[3];
    const float* b1a  = (const float*)d_in[4];
    const float* w2a  = (const float*)d_in[5];
    const float* b2a  = (const float*)d_in[6];
    const float* w1b  = (const float*)d_in[7];
    const float* b1b  = (const float*)d_in[8];
    const float* w2b  = (const float*)d_in[9];
    const float* b2b  = (const float*)d_in[10];
    float* out = (float*)d_out;

    char* ws = (char*)d_ws;
    float* ws_logits = (float*)(ws + WS_LOGITS_OFF);
    int*   ws_cand   = (int*)  (ws + WS_CAND_OFF);
    float* ws_exact  = (float*)(ws + WS_EXACT_OFF);
    int*   ws_cnt    = (int*)  (ws + WS_CNT_OFF);
    int*   ws_topk   = (int*)  (ws + WS_TOPK_OFF);
    float* ws_pf     = (float*)(ws + WS_PF_OFF);
    u16*   ws_wh     = (u16*)  (ws + WS_WH_OFF);
    u16*   ws_wl     = (u16*)  (ws + WS_WL_OFF);

    hipMemsetAsync(ws_logits, 0, 16384 * sizeof(float), stream);

    k0_splitW<<<16, 256, 0, stream>>>(w1a, ws_wh, ws_wl);
    k1_pair_mfma<<<dim3(2, NN, RR), 256, 0, stream>>>(obj, geo, ws_wh, ws_wl, b1a, w2a, ws_logits);
    k2_hist<<<1, 1024, 0, stream>>>(ws_logits, mask, b2a, out, ws_cand, ws_cnt);
    k5_exact<<<NCAND, 256, 0, stream>>>(obj, geo, w1a, b1a, w2a, b2a, ws_cand, ws_cnt, ws_exact);
    k_sort<<<1, 256, 0, stream>>>(ws_exact, ws_cand, out, ws_topk);
    k3_gather<<<KTOP, 256, 0, stream>>>(obj, geo, ws_topk, ws_pf);
    k4_p2p<<<KTOP, 256, 0, stream>>>(ws_pf, w1b, b1b, w2b, b2b, out);
}